// Round 8
// baseline (140.615 us; speedup 1.0000x reference)
//
#include <hip/hip_runtime.h>
#include <math.h>

#define T_SAMPLES 16384
#define BC 128            // 64 batch * 2 channels
#define NUM_FREQS 257
#define NUM_TIMES 513
#define JT 57             // 513 = 9 * 57 output columns per block

typedef float vf2 __attribute__((ext_vector_type(2)));

// ---------- compile-time trig tables (no runtime sincosf) ----------
constexpr double CPI = 3.14159265358979323846;
constexpr double ctsin(double x) {
    double x2 = x * x, t = x, s = x;
    for (int n = 1; n <= 12; ++n) { t *= -x2 / (double)((2*n) * (2*n + 1)); s += t; }
    return s;
}
constexpr double ctcos(double x) {
    double x2 = x * x, t = 1.0, s = 1.0;
    for (int n = 1; n <= 12; ++n) { t *= -x2 / (double)((2*n - 1) * (2*n)); s += t; }
    return s;
}
struct Tables {
    float twe[6][64][2];   // stage twiddle, hi-folding baked in (lo lanes = 1)
    float twL[3][64][2];   // tw6 / tw7 / tw8 per lane
    float win[4][512];     // periodic Hann per resolution (N = 64<<r)
};
constexpr Tables make_tables() {
    Tables T{};
    for (int b = 0; b < 6; ++b)
        for (int l = 0; l < 64; ++l) {
            const bool hi = (l >> b) & 1;
            const int  k  = l & ((1 << b) - 1);
            const double a = -2.0 * CPI * (double)k / (double)(1 << (b + 1));
            T.twe[b][l][0] = hi ? (float)ctcos(a) : 1.0f;
            T.twe[b][l][1] = hi ? (float)ctsin(a) : 0.0f;
        }
    for (int i = 0; i < 3; ++i)
        for (int l = 0; l < 64; ++l) {
            const double a = -2.0 * CPI * (double)l / (double)(128 << i);
            T.twL[i][l][0] = (float)ctcos(a);
            T.twL[i][l][1] = (float)ctsin(a);
        }
    for (int r = 0; r < 4; ++r) {
        const int N = 64 << r;
        for (int n = 0; n < N; ++n) {
            const int m = (2 * n <= N) ? n : n - N;
            const double a = 2.0 * CPI * (double)m / (double)N;
            T.win[r][n] = (float)(0.5 - 0.5 * ctcos(a));
        }
    }
    return T;
}
__device__ __constant__ Tables g_tab = make_tables();
// -------------------------------------------------------------------

__device__ inline vf2 cmul(vf2 a, vf2 b) {
    vf2 ar = { -a.y, a.x };
    return b.x * a + b.y * ar;
}

// DPP lane exchange within quads (free quad_perm): 0xB1 = xor1, 0x4E = xor2
template <int CTRL>
__device__ inline float dppf(float x) {
    return __builtin_bit_cast(float,
        __builtin_amdgcn_update_dpp(0, __builtin_bit_cast(int, x),
                                    CTRL, 0xF, 0xF, true));
}

// One resolution, fused: FFT the frame pairs [p_lo, p_lo+np) (packed-real,
// z = x[2m] + i*x[2m+1], KLOOP slots per wave for ILP), then in batches of
// NB pairs: scatter Z (bit-reversal resolved) into swizzled SoA zbuf,
// Hermitian-separate into the per-res power tile ptile[F][COLS] in LDS.
// COLS = 2*maxpairs for this res.
template <int LOGN, int KLOOP, int NB, int COLS>
__device__ void fft_res_fused(const float* __restrict__ xb, int p_lo, int np,
                              float* __restrict__ ptile, float* __restrict__ zbuf) {
    constexpr int N      = 1 << LOGN;
    constexpr int HOP    = N / 2;
    constexpr int F      = HOP + 1;
    constexpr int NT     = T_SAMPLES / HOP + 1;
    constexpr int R      = N / 64;
    constexpr int RS     = N + N / 32 + 1;       // odd row stride
    constexpr int MAXP   = COLS / 2;
    constexpr int NBATCH = (MAXP + NB - 1) / NB;
    const float NORM4    = 0.25f * 8.0f / (3.0f * (float)N);

    const int tid  = threadIdx.x;
    const int lane = tid & 63;
    const int wave = tid >> 6;

    float sgn[6];
    vf2   twe[6];
#pragma unroll
    for (int b = 0; b < 6; ++b) {
        twe[b] = *(const vf2*)g_tab.twe[b][lane];
        sgn[b] = ((lane >> b) & 1) ? -1.0f : 1.0f;
    }
    vf2 tw6 = {1,0}, tw7 = {1,0}, tw8 = {1,0};
    if constexpr (LOGN >= 7) tw6 = *(const vf2*)g_tab.twL[0][lane];
    if constexpr (LOGN >= 8) tw7 = *(const vf2*)g_tab.twL[1][lane];
    if constexpr (LOGN >= 9) tw8 = *(const vf2*)g_tab.twL[2][lane];

    float wr[R];
#pragma unroll
    for (int r = 0; r < R; ++r) wr[r] = g_tab.win[LOGN - 6][r * 64 + lane];

    vf2 d[KLOOP][R];

    // ---- load all slots (wave-uniform boundary tests) ----
#pragma unroll
    for (int q = 0; q < KLOOP; ++q) {
        const int p = q * 4 + wave;
        if (p < np) {
            const int pg = p_lo + p;
            const int t1 = 2 * pg, t2 = t1 + 1;
            const bool refl = (t1 == 0) || (t1 * HOP + N - 1 >= T_SAMPLES) || (t2 >= NT);
            if (!refl) {
                const float* src = xb + t1 * HOP - HOP;
#pragma unroll
                for (int r = 0; r < R; ++r) {
                    int n = r * 64 + lane;
                    vf2 v = { src[n], src[n + HOP] };
                    d[q][r] = v * wr[r];
                }
            } else {
#pragma unroll
                for (int r = 0; r < R; ++r) {
                    int n = r * 64 + lane;
                    int g = t1 * HOP + n - HOP;
                    g = (g < 0) ? -g : g;
                    g = (g >= T_SAMPLES) ? (2 * T_SAMPLES - 2 - g) : g;
                    float re = xb[g] * wr[r];
                    float im = 0.0f;
                    if (t2 < NT) {
                        int h = t2 * HOP + n - HOP;
                        h = (h < 0) ? -h : h;
                        h = (h >= T_SAMPLES) ? (2 * T_SAMPLES - 2 - h) : h;
                        im = xb[h] * wr[r];
                    }
                    d[q][r] = { re, im };
                }
            }
        } else {
#pragma unroll
            for (int r = 0; r < R; ++r) d[q][r] = vf2{0.0f, 0.0f};
        }
    }

    // ---- in-register DIF stages (bits 8,7,6) ----
    if constexpr (LOGN >= 9) {
        const vf2 u8 = { 0.70710678118654752f, -0.70710678118654752f };
#pragma unroll
        for (int q = 0; q < KLOOP; ++q) {
            vf2 tt = tw8;
#pragma unroll
            for (int r = 0; r < 4; ++r) {
                vf2 a = d[q][r], b = d[q][r + 4];
                d[q][r]     = a + b;
                d[q][r + 4] = cmul(a - b, tt);
                tt = cmul(tt, u8);
            }
        }
    }
    if constexpr (LOGN >= 8) {
        const vf2 t0_ = tw7;
        const vf2 t1_ = { tw7.y, -tw7.x };
#pragma unroll
        for (int q = 0; q < KLOOP; ++q) {
#pragma unroll
            for (int g = 0; g < R; g += 4) {
                { vf2 a = d[q][g],   b = d[q][g+2]; d[q][g]   = a + b; d[q][g+2] = cmul(a - b, t0_); }
                { vf2 a = d[q][g+1], b = d[q][g+3]; d[q][g+1] = a + b; d[q][g+3] = cmul(a - b, t1_); }
            }
        }
    }
    if constexpr (LOGN >= 7) {
#pragma unroll
        for (int q = 0; q < KLOOP; ++q) {
#pragma unroll
            for (int g = 0; g < R; g += 2) {
                vf2 a = d[q][g], b = d[q][g+1];
                d[q][g]   = a + b;
                d[q][g+1] = cmul(a - b, tw6);
            }
        }
    }

    // ---- cross-lane stages b=5..2 (shfl_xor) ----
#pragma unroll
    for (int b = 5; b >= 2; --b) {
        const int   mask = 1 << b;
        const vf2   w    = twe[b];
        const float s    = sgn[b];
#pragma unroll
        for (int q = 0; q < KLOOP; ++q) {
#pragma unroll
            for (int r = 0; r < R; ++r) {
                vf2 p2;
                p2.x = __shfl_xor(d[q][r].x, mask, 64);
                p2.y = __shfl_xor(d[q][r].y, mask, 64);
                vf2 t  = p2 + d[q][r] * s;
                vf2 tr = { -t.y, t.x };
                d[q][r] = w.x * t + w.y * tr;
            }
        }
    }
    // ---- b=1: DPP quad_perm xor2 ----
    {
        const vf2   w = twe[1];
        const float s = sgn[1];
#pragma unroll
        for (int q = 0; q < KLOOP; ++q) {
#pragma unroll
            for (int r = 0; r < R; ++r) {
                vf2 p2 = { dppf<0x4E>(d[q][r].x), dppf<0x4E>(d[q][r].y) };
                vf2 t  = p2 + d[q][r] * s;
                vf2 tr = { -t.y, t.x };
                d[q][r] = w.x * t + w.y * tr;
            }
        }
    }
    // ---- b=0: DPP quad_perm xor1, twiddle == 1 ----
    {
        const float s = sgn[0];
#pragma unroll
        for (int q = 0; q < KLOOP; ++q) {
#pragma unroll
            for (int r = 0; r < R; ++r) {
                vf2 p2 = { dppf<0xB1>(d[q][r].x), dppf<0xB1>(d[q][r].y) };
                d[q][r] = p2 + d[q][r] * s;
            }
        }
    }

    // ---- batched scatter + Hermitian separation into the LDS power tile ----
#pragma unroll
    for (int b = 0; b < NBATCH; ++b) {
        const int blo = b * NB;
#pragma unroll
        for (int q = 0; q < KLOOP; ++q) {
            const int p = q * 4 + wave;
            if (p >= blo && p < blo + NB && p < np) {
#pragma unroll
                for (int r = 0; r < R; ++r) {
                    int idx = r * 64 + lane;
                    int f   = (int)(__brev((unsigned)idx) >> (32 - LOGN));
                    int pos = (p - blo) * RS + f + (f >> 5);
                    zbuf[pos]           = d[q][r].x;
                    zbuf[pos + NB * RS] = d[q][r].y;
                }
            }
        }
        __syncthreads();
        for (int e = tid; e < F * NB; e += 256) {
            int f  = e / NB;
            int pb = e - f * NB;
            int p  = blo + pb;
            if (p < np) {
                int fn = (N - f) & (N - 1);
                int pa = pb * RS + f  + (f  >> 5);
                int pc = pb * RS + fn + (fn >> 5);
                float ax = zbuf[pa], ay = zbuf[pa + NB * RS];
                float bx = zbuf[pc], by = zbuf[pc + NB * RS];
                float rx = ax + bx, ry = ay - by;          // X1 = (Z + conj(Zn))/2
                ptile[f * COLS + 2 * p] = (rx * rx + ry * ry) * NORM4;
                int tg = 2 * (p_lo + p);
                if (tg + 1 < NT) {
                    float sx = ax - bx, sy = ay + by;      // X2 = (Z - conj(Zn))/2i
                    ptile[f * COLS + 2 * p + 1] = (sx * sx + sy * sy) * NORM4;
                }
            }
        }
        __syncthreads();
    }
}

// Fully fused: per (bc, 57-column tile), compute all four resolutions' power
// tiles in LDS, then gather-max + write output directly. No workspace.
__global__ __launch_bounds__(256) void spec_fused_kernel(const float* __restrict__ x,
                                                         float* __restrict__ out) {
    // LDS layout (floats): pt0 33*58 | pt1 65*32 | pt2 129*18 | pt3 257*12 | zbuf 3886
    __shared__ float smem[13286];   // 53144 B -> 3 blocks/CU
    float* pt0  = smem;
    float* pt1  = smem + 1914;
    float* pt2  = smem + 3994;
    float* pt3  = smem + 6316;
    float* zbuf = smem + 9400;

    const int k  = blockIdx.x;      // tile 0..8
    const int bc = blockIdx.y;
    const int j0 = k * JT;
    const float* xb = x + (size_t)bc * T_SAMPLES;

    // pair ranges per resolution (constant divisors -> magic muls)
    const int plo0 = j0 >> 1;
    const int np0  = ((j0 + JT - 1) >> 1) - plo0 + 1;                       // == 29
    const int plo1 = ((j0 * 257) / 513) >> 1;
    const int np1  = ((((j0 + JT - 1) * 257) / 513) >> 1) - plo1 + 1;       // <= 16
    const int plo2 = ((j0 * 129) / 513) >> 1;
    const int np2  = ((((j0 + JT - 1) * 129) / 513) >> 1) - plo2 + 1;       // <= 9
    const int plo3 = ((j0 * 65) / 513) >> 1;
    const int np3  = ((((j0 + JT - 1) * 65) / 513) >> 1) - plo3 + 1;        // <= 6

    fft_res_fused<6, 8, 29, 58>(xb, plo0, np0, pt0, zbuf);
    fft_res_fused<7, 4,  8, 32>(xb, plo1, np1, pt1, zbuf);
    fft_res_fused<8, 3,  5, 18>(xb, plo2, np2, pt2, zbuf);
    fft_res_fused<9, 2,  3, 12>(xb, plo3, np3, pt3, zbuf);
    // (each res ends with __syncthreads; tiles are visible)

    // ---- remap-max from LDS tiles, coalesced output write ----
    const int tb0 = 2 * plo0, tb1 = 2 * plo1, tb2 = 2 * plo2, tb3 = 2 * plo3;
    float* outb = out + (size_t)bc * NUM_FREQS * NUM_TIMES;
    for (int e = threadIdx.x; e < NUM_FREQS * JT; e += 256) {
        int i  = e / JT;
        int jl = e - i * JT;
        int j  = j0 + jl;
        float m;
        { int fi = (i * 33) / 257;                           m = pt0[fi * 58 + (j - tb0)]; }
        { int fi = (i * 65) / 257;  int ti = (j * 257) / 513; m = fmaxf(m, pt1[fi * 32 + (ti - tb1)]); }
        { int fi = (i * 129) / 257; int ti = (j * 129) / 513; m = fmaxf(m, pt2[fi * 18 + (ti - tb2)]); }
        {                           int ti = (j * 65) / 513;  m = fmaxf(m, pt3[(size_t)i * 12 + (ti - tb3)]); }
        outb[(size_t)i * NUM_TIMES + j] = m;
    }
}

extern "C" void kernel_launch(void* const* d_in, const int* in_sizes, int n_in,
                              void* d_out, int out_size, void* d_ws, size_t ws_size,
                              hipStream_t stream) {
    const float* x = (const float*)d_in[0];
    float* out = (float*)d_out;
    spec_fused_kernel<<<dim3(9, BC), 256, 0, stream>>>(x, out);
}

// Round 9
// 119.492 us; speedup vs baseline: 1.1768x; 1.1768x over previous
//
#include <hip/hip_runtime.h>
#include <math.h>

#define T_SAMPLES 16384
#define BC 128            // 64 batch * 2 channels
#define NUM_FREQS 257
#define NUM_TIMES 513

// Workspace: fp16 spectra, TRANSPOSED [bc][f][t], row stride padded to %4==0:
//  r0: N=64   F=33  NT=513 NTP=516   r1: N=128  F=65  NT=257 NTP=260
//  r2: N=256  F=129 NT=129 NTP=132   r3: N=512  F=257 NT=65  NTP=68
// offsets in HALF units:
#define OFF0 0
#define OFF1 2179584      // 128*33*516
#define OFF2 4342784      // + 128*65*260
#define OFF3 6522368      // + 128*129*132
// total 8,759,296 halves = 17.5 MB of d_ws

typedef float    vf2 __attribute__((ext_vector_type(2)));
typedef float    vf4 __attribute__((ext_vector_type(4)));
typedef vf4 vf4u __attribute__((aligned(4)));   // unaligned-capable float4
typedef _Float16 vh2 __attribute__((ext_vector_type(2)));
typedef _Float16 vh4 __attribute__((ext_vector_type(4)));

// ---------- compile-time trig tables (no runtime sincosf) ----------
constexpr double CPI = 3.14159265358979323846;
constexpr double ctsin(double x) {
    double x2 = x * x, t = x, s = x;
    for (int n = 1; n <= 12; ++n) { t *= -x2 / (double)((2*n) * (2*n + 1)); s += t; }
    return s;
}
constexpr double ctcos(double x) {
    double x2 = x * x, t = 1.0, s = 1.0;
    for (int n = 1; n <= 12; ++n) { t *= -x2 / (double)((2*n - 1) * (2*n)); s += t; }
    return s;
}
struct Tables {
    // lane-major: [lane][0..5]=stage twiddles (hi-folded), [6..8]=tw6..tw8, [9]=pad
    // 80 B per lane -> 16B-aligned -> 5 float4 loads
    float lane_tw[64][10][2];
    float win[4][512];     // periodic Hann per resolution (N = 64<<r)
};
constexpr Tables make_tables() {
    Tables T{};
    for (int l = 0; l < 64; ++l) {
        for (int b = 0; b < 6; ++b) {
            const bool hi = (l >> b) & 1;
            const int  k  = l & ((1 << b) - 1);
            const double a = -2.0 * CPI * (double)k / (double)(1 << (b + 1));
            T.lane_tw[l][b][0] = hi ? (float)ctcos(a) : 1.0f;
            T.lane_tw[l][b][1] = hi ? (float)ctsin(a) : 0.0f;
        }
        for (int i = 0; i < 3; ++i) {
            const double a = -2.0 * CPI * (double)l / (double)(128 << i);
            T.lane_tw[l][6 + i][0] = (float)ctcos(a);
            T.lane_tw[l][6 + i][1] = (float)ctsin(a);
        }
        T.lane_tw[l][9][0] = 0.0f; T.lane_tw[l][9][1] = 0.0f;
    }
    for (int r = 0; r < 4; ++r) {
        const int N = 64 << r;
        for (int n = 0; n < N; ++n) {
            const int m = (2 * n <= N) ? n : n - N;
            const double a = 2.0 * CPI * (double)m / (double)N;
            T.win[r][n] = (float)(0.5 - 0.5 * ctcos(a));
        }
    }
    return T;
}
__device__ __constant__ Tables g_tab = make_tables();
// -------------------------------------------------------------------

__device__ inline vf2 cmul(vf2 a, vf2 b) {
    vf2 ar = { -a.y, a.x };
    return b.x * a + b.y * ar;
}

// DPP lane exchange within quads (free quad_perm): 0xB1 = xor1, 0x4E = xor2
template <int CTRL>
__device__ inline float dppf(float x) {
    return __builtin_bit_cast(float,
        __builtin_amdgcn_update_dpp(0, __builtin_bit_cast(int, x),
                                    CTRL, 0xF, 0xF, true));
}

// Packed-real shuffle FFT, batched for ILP: one wave owns KLOOP = P/4
// CONTIGUOUS frame pairs (z = x[2m] + i*x[2m+1]); KLOOP*R == 8 independent
// butterfly chains per wave. DIF: register stages (bits >= 6) in-register;
// lane stages b=5..2 via shfl_xor, b=1..0 via DPP quad_perm. Twiddles/window
// from compile-time constant tables (5x float4 per lane). Full Z scattered
// (bit-reversal resolved) into swizzled SoA LDS (odd row stride); Hermitian
// separation fused into a coalesced transposed fp16 write (X1,X2 per half2).
template <int LOGN, int P>
__device__ void fft_tile_body(const float* __restrict__ x, _Float16* __restrict__ spec,
                              int tile, int bc, float* smem) {
    constexpr int N     = 1 << LOGN;
    constexpr int HOP   = N / 2;
    constexpr int F     = HOP + 1;
    constexpr int NT    = T_SAMPLES / HOP + 1;
    constexpr int NTP   = (NT + 3) & ~3;    // padded row stride (halves), %4==0
    constexpr int NPAIR = (NT + 1) / 2;
    constexpr int R     = N / 64;
    constexpr int RS    = N + N / 32 + 1;   // ODD row stride: p*RS is a bank permutation
    constexpr int KLOOP = P / 4;            // pairs per wave (KLOOP*R == 8)
    const float NORM4   = 0.25f * 8.0f / (3.0f * (float)N);  // 1/(4*sum(w^2))

    float* zre = smem;
    float* zim = smem + P * RS;

    const int tid   = threadIdx.x;
    const int lane  = tid & 63;
    const int wave  = tid >> 6;
    const int pair0 = tile * P;
    const int t0    = pair0 * 2;

    // packed table loads: 5 float4 per lane
    float sgn[6];
    vf2   twe[6];
    vf2   tw6 = {1,0}, tw7 = {1,0}, tw8 = {1,0};
    {
        const vf4* twp = (const vf4*)g_tab.lane_tw[lane];
        vf4 A = twp[0], B = twp[1], C = twp[2], D = twp[3], E = twp[4];
        twe[0] = {A.x, A.y}; twe[1] = {A.z, A.w};
        twe[2] = {B.x, B.y}; twe[3] = {B.z, B.w};
        twe[4] = {C.x, C.y}; twe[5] = {C.z, C.w};
        if constexpr (LOGN >= 7) tw6 = {D.x, D.y};
        if constexpr (LOGN >= 8) tw7 = {D.z, D.w};
        if constexpr (LOGN >= 9) tw8 = {E.x, E.y};
#pragma unroll
        for (int b = 0; b < 6; ++b) sgn[b] = ((lane >> b) & 1) ? -1.0f : 1.0f;
    }

    float wr[R];
#pragma unroll
    for (int r = 0; r < R; ++r) wr[r] = g_tab.win[LOGN - 6][r * 64 + lane];

    const float* xb = x + (size_t)bc * T_SAMPLES;

    vf2  d[KLOOP][R];
    bool act[KLOOP];

    // ---- load all pairs up front; contiguous per wave (L1 locality) ----
#pragma unroll
    for (int q = 0; q < KLOOP; ++q) {
        const int p  = wave * KLOOP + q;
        const int pg = pair0 + p;
        act[q] = (pg < NPAIR);
        if (act[q]) {
            const int t1 = 2 * pg, t2 = t1 + 1;
            const bool refl = (t1 == 0) || (t1 * HOP + N - 1 >= T_SAMPLES) || (t2 >= NT);
            if (!refl) {
                const float* src = xb + t1 * HOP - HOP;
#pragma unroll
                for (int r = 0; r < R; ++r) {
                    int n = r * 64 + lane;
                    vf2 v = { src[n], src[n + HOP] };
                    d[q][r] = v * wr[r];
                }
            } else {
#pragma unroll
                for (int r = 0; r < R; ++r) {
                    int n = r * 64 + lane;
                    int g = t1 * HOP + n - HOP;
                    g = (g < 0) ? -g : g;
                    g = (g >= T_SAMPLES) ? (2 * T_SAMPLES - 2 - g) : g;
                    float re = xb[g] * wr[r];
                    float im = 0.0f;
                    if (t2 < NT) {
                        int h = t2 * HOP + n - HOP;
                        h = (h < 0) ? -h : h;
                        h = (h >= T_SAMPLES) ? (2 * T_SAMPLES - 2 - h) : h;
                        im = xb[h] * wr[r];
                    }
                    d[q][r] = { re, im };
                }
            }
        } else {
#pragma unroll
            for (int r = 0; r < R; ++r) d[q][r] = vf2{0.0f, 0.0f};
        }
    }

    // ---- in-register DIF stages (bits 8,7,6), all pairs ----
    if constexpr (LOGN >= 9) {
        const vf2 u8 = { 0.70710678118654752f, -0.70710678118654752f };
#pragma unroll
        for (int q = 0; q < KLOOP; ++q) {
            vf2 tt = tw8;
#pragma unroll
            for (int r = 0; r < 4; ++r) {
                vf2 a = d[q][r], b = d[q][r + 4];
                d[q][r]     = a + b;
                d[q][r + 4] = cmul(a - b, tt);
                tt = cmul(tt, u8);
            }
        }
    }
    if constexpr (LOGN >= 8) {
        const vf2 t0_ = tw7;
        const vf2 t1_ = { tw7.y, -tw7.x };
#pragma unroll
        for (int q = 0; q < KLOOP; ++q) {
#pragma unroll
            for (int g = 0; g < R; g += 4) {
                { vf2 a = d[q][g],   b = d[q][g+2]; d[q][g]   = a + b; d[q][g+2] = cmul(a - b, t0_); }
                { vf2 a = d[q][g+1], b = d[q][g+3]; d[q][g+1] = a + b; d[q][g+3] = cmul(a - b, t1_); }
            }
        }
    }
    if constexpr (LOGN >= 7) {
#pragma unroll
        for (int q = 0; q < KLOOP; ++q) {
#pragma unroll
            for (int g = 0; g < R; g += 2) {
                vf2 a = d[q][g], b = d[q][g+1];
                d[q][g]   = a + b;
                d[q][g+1] = cmul(a - b, tw6);
            }
        }
    }

    // ---- cross-lane stages b=5..2 (shfl_xor), 8 independent chains ----
#pragma unroll
    for (int b = 5; b >= 2; --b) {
        const int   mask = 1 << b;
        const vf2   w    = twe[b];
        const float s    = sgn[b];
#pragma unroll
        for (int q = 0; q < KLOOP; ++q) {
#pragma unroll
            for (int r = 0; r < R; ++r) {
                vf2 p2;
                p2.x = __shfl_xor(d[q][r].x, mask, 64);
                p2.y = __shfl_xor(d[q][r].y, mask, 64);
                vf2 t  = p2 + d[q][r] * s;
                vf2 tr = { -t.y, t.x };
                d[q][r] = w.x * t + w.y * tr;
            }
        }
    }
    // ---- b=1: DPP quad_perm xor2 ----
    {
        const vf2   w = twe[1];
        const float s = sgn[1];
#pragma unroll
        for (int q = 0; q < KLOOP; ++q) {
#pragma unroll
            for (int r = 0; r < R; ++r) {
                vf2 p2 = { dppf<0x4E>(d[q][r].x), dppf<0x4E>(d[q][r].y) };
                vf2 t  = p2 + d[q][r] * s;
                vf2 tr = { -t.y, t.x };
                d[q][r] = w.x * t + w.y * tr;
            }
        }
    }
    // ---- b=0: DPP quad_perm xor1, twiddle == 1 ----
    {
        const float s = sgn[0];
#pragma unroll
        for (int q = 0; q < KLOOP; ++q) {
#pragma unroll
            for (int r = 0; r < R; ++r) {
                vf2 p2 = { dppf<0xB1>(d[q][r].x), dppf<0xB1>(d[q][r].y) };
                d[q][r] = p2 + d[q][r] * s;
            }
        }
    }

    // ---- scatter full Z, bit-reversal resolved; (f>>5) swizzle: <=2-way ----
#pragma unroll
    for (int q = 0; q < KLOOP; ++q) {
        if (act[q]) {
            const int p = wave * KLOOP + q;
#pragma unroll
            for (int r = 0; r < R; ++r) {
                int idx = r * 64 + lane;
                int f   = (int)(__brev((unsigned)idx) >> (32 - LOGN));
                int pos = p * RS + f + (f >> 5);
                zre[pos] = d[q][r].x;
                zim[pos] = d[q][r].y;
            }
        }
    }
    __syncthreads();

    // Hermitian separation: X1 (t even) + X2 (t odd) from one (Z[f],Z[N-f])
    // pair, packed into a single aligned half2 store (t0+2p even, NTP even).
    _Float16* sbase = spec + (size_t)bc * F * NTP;
    for (int e = tid; e < F * P; e += 256) {
        int f = e / P;                     // P is a power of two
        int p = e % P;
        int t = t0 + 2 * p;
        if (t < NT) {                      // matches act: pair0+p < NPAIR
            int fn = (N - f) & (N - 1);
            int pa = p * RS + f  + (f  >> 5);
            int pb = p * RS + fn + (fn >> 5);
            float ax = zre[pa], ay = zim[pa];
            float bx = zre[pb], by = zim[pb];
            float rx = ax + bx, ry = ay - by;          // X1 = (Z + conj(Zn))/2
            float sx = ax - bx, sy = ay + by;          // X2 = (Z - conj(Zn))/2i
            vh2 pv = { (_Float16)((rx * rx + ry * ry) * NORM4),
                       (_Float16)((sx * sx + sy * sy) * NORM4) };   // X2 of last col lands in pad
            *(vh2*)(sbase + (size_t)f * NTP + t) = pv;
        }
    }
}

// Fused kernel, uniform 9 tiles per resolution:
// bx in [0,9) N=64 | [9,18) N=128 | [18,27) N=256 | [27,36) N=512
__global__ __launch_bounds__(256) void fft_all_kernel(const float* __restrict__ x,
                                                      _Float16* __restrict__ ws) {
    __shared__ float smem[4288];   // max 2*P*RS floats = 17152 B (res0)
    const int bx = blockIdx.x;
    const int bc = blockIdx.y;
    if (bx < 9)        fft_tile_body<6, 32>(x, ws + OFF0, bx,      bc, smem);
    else if (bx < 18)  fft_tile_body<7, 16>(x, ws + OFF1, bx - 9,  bc, smem);
    else if (bx < 27)  fft_tile_body<8, 8> (x, ws + OFF2, bx - 18, bc, smem);
    else               fft_tile_body<9, 4> (x, ws + OFF3, bx - 27, bc, smem);
}

// 4 output columns (j) per thread; res-0 gather is a contiguous aligned half4;
// res1-3 scalar half gathers; float4 output store (unaligned-capable).
__global__ __launch_bounds__(256) void remap_max_kernel(const _Float16* __restrict__ ws,
                                                        float* __restrict__ out) {
    const int JG    = 129;                    // ceil(513/4)
    const int total = BC * NUM_FREQS * JG;
    int idx = blockIdx.x * 256 + threadIdx.x;
    if (idx >= total) return;
    int jg  = idx % JG;
    int rem = idx / JG;
    int i   = rem % NUM_FREQS;
    int bc  = rem / NUM_FREQS;
    int j0  = jg * 4;
    const bool full = (j0 + 3 < NUM_TIMES);

    float mv[4];
    {   // r0: ti == j exactly; stride 516 (%4==0) + j0 (%4==0) -> 8B-aligned half4
        int fi = (i * 33) / NUM_FREQS;
        const _Float16* p = ws + OFF0 + ((size_t)bc * 33 + fi) * 516 + j0;
        if (full) {
            vh4 v = *(const vh4*)p;
            mv[0] = (float)v.x; mv[1] = (float)v.y; mv[2] = (float)v.z; mv[3] = (float)v.w;
        } else {
            mv[0] = (float)p[0]; mv[1] = mv[2] = mv[3] = 0.0f;
        }
    }
#pragma unroll
    for (int k = 0; k < 4; ++k) {
        int j = j0 + k;
        if (j < NUM_TIMES) {
#define GATHER(OFF, F_, NT_, NTP_)                                             \
            {                                                                  \
                int fi = (i * F_) / NUM_FREQS;                                 \
                int ti = (j * NT_) / NUM_TIMES;                                \
                float v = (float)ws[(size_t)(OFF) + ((size_t)bc * (F_) + fi) * (NTP_) + ti]; \
                mv[k] = fmaxf(mv[k], v);                                       \
            }
            GATHER(OFF1, 65, 257, 260)
            GATHER(OFF2, 129, 129, 132)
            GATHER(OFF3, 257, 65, 68)
#undef GATHER
        }
    }

    float* po = out + ((size_t)bc * NUM_FREQS + i) * NUM_TIMES + j0;
    if (full) {
        vf4 v = { mv[0], mv[1], mv[2], mv[3] };
        *(vf4u*)po = v;
    } else {
        po[0] = mv[0];
    }
}

extern "C" void kernel_launch(void* const* d_in, const int* in_sizes, int n_in,
                              void* d_out, int out_size, void* d_ws, size_t ws_size,
                              hipStream_t stream) {
    const float* x = (const float*)d_in[0];
    _Float16* ws = (_Float16*)d_ws;
    float* out = (float*)d_out;

    fft_all_kernel<<<dim3(36, BC), 256, 0, stream>>>(x, ws);

    const int total = BC * NUM_FREQS * 129;
    remap_max_kernel<<<(total + 255) / 256, 256, 0, stream>>>(ws, out);
}

// Round 10
// 115.816 us; speedup vs baseline: 1.2141x; 1.0317x over previous
//
#include <hip/hip_runtime.h>
#include <math.h>

#define T_SAMPLES 16384
#define BC 128            // 64 batch * 2 channels
#define NUM_FREQS 257
#define NUM_TIMES 513

// Workspace: fp16 spectra, TRANSPOSED [bc][f][t], row stride padded to %4==0:
//  r0: N=64   F=33  NT=513 NTP=516   r1: N=128  F=65  NT=257 NTP=260
//  r2: N=256  F=129 NT=129 NTP=132   r3: N=512  F=257 NT=65  NTP=68
// offsets in HALF units:
#define OFF0 0
#define OFF1 2179584      // 128*33*516
#define OFF2 4342784      // + 128*65*260
#define OFF3 6522368      // + 128*129*132

typedef float    vf2 __attribute__((ext_vector_type(2)));
typedef float    vf4 __attribute__((ext_vector_type(4)));
typedef vf4 vf4u __attribute__((aligned(4)));   // unaligned-capable float4
typedef _Float16 vh2 __attribute__((ext_vector_type(2)));
typedef _Float16 vh4 __attribute__((ext_vector_type(4)));

// ---------- compile-time trig tables (no runtime sincosf) ----------
constexpr double CPI = 3.14159265358979323846;
constexpr double ctsin(double x) {
    double x2 = x * x, t = x, s = x;
    for (int n = 1; n <= 12; ++n) { t *= -x2 / (double)((2*n) * (2*n + 1)); s += t; }
    return s;
}
constexpr double ctcos(double x) {
    double x2 = x * x, t = 1.0, s = 1.0;
    for (int n = 1; n <= 12; ++n) { t *= -x2 / (double)((2*n - 1) * (2*n)); s += t; }
    return s;
}
struct Tables {
    // lane-major: [lane][0..5]=stage twiddles (hi-folded), [6..8]=tw6..tw8, [9]=pad
    float lane_tw[64][10][2];   // 80 B/lane -> 5 float4 loads
    float win[4][512];          // periodic Hann per resolution (N = 64<<r)
};
constexpr Tables make_tables() {
    Tables T{};
    for (int l = 0; l < 64; ++l) {
        for (int b = 0; b < 6; ++b) {
            const bool hi = (l >> b) & 1;
            const int  k  = l & ((1 << b) - 1);
            const double a = -2.0 * CPI * (double)k / (double)(1 << (b + 1));
            T.lane_tw[l][b][0] = hi ? (float)ctcos(a) : 1.0f;
            T.lane_tw[l][b][1] = hi ? (float)ctsin(a) : 0.0f;
        }
        for (int i = 0; i < 3; ++i) {
            const double a = -2.0 * CPI * (double)l / (double)(128 << i);
            T.lane_tw[l][6 + i][0] = (float)ctcos(a);
            T.lane_tw[l][6 + i][1] = (float)ctsin(a);
        }
        T.lane_tw[l][9][0] = 0.0f; T.lane_tw[l][9][1] = 0.0f;
    }
    for (int r = 0; r < 4; ++r) {
        const int N = 64 << r;
        for (int n = 0; n < N; ++n) {
            const int m = (2 * n <= N) ? n : n - N;
            const double a = 2.0 * CPI * (double)m / (double)N;
            T.win[r][n] = (float)(0.5 - 0.5 * ctcos(a));
        }
    }
    return T;
}
__device__ __constant__ Tables g_tab = make_tables();
// -------------------------------------------------------------------

__device__ inline vf2 cmul(vf2 a, vf2 b) {
    vf2 ar = { -a.y, a.x };
    return b.x * a + b.y * ar;
}

// DPP lane exchange within quads (free quad_perm): 0xB1 = xor1, 0x4E = xor2
template <int CTRL>
__device__ inline float dppf(float x) {
    return __builtin_bit_cast(float,
        __builtin_amdgcn_update_dpp(0, __builtin_bit_cast(int, x),
                                    CTRL, 0xF, 0xF, true));
}

// Packed-real shuffle FFT, batched for ILP: one wave owns KLOOP = P/4
// CONTIGUOUS frame pairs (z = x[2m] + i*x[2m+1]); KLOOP*R == 8 independent
// butterfly chains per wave. DIF: register stages (bits >= 6) in-register;
// lane stages b=5..2 via shfl_xor, b=1..0 via DPP quad_perm. Full Z scattered
// (bit-reversal resolved) into an interleaved float2 LDS buffer (b64 ops,
// pos = p*RS2 + f + (f>>4), odd RS2 -> bank permutation); Hermitian
// separation fused into a coalesced transposed fp16 write (X1,X2 per half2).
template <int LOGN, int P>
__device__ void fft_tile_body(const float* __restrict__ x, _Float16* __restrict__ spec,
                              int tile, int bc, vf2* __restrict__ zb) {
    constexpr int N     = 1 << LOGN;
    constexpr int HOP   = N / 2;
    constexpr int F     = HOP + 1;
    constexpr int NT    = T_SAMPLES / HOP + 1;
    constexpr int NTP   = (NT + 3) & ~3;    // padded row stride (halves), %4==0
    constexpr int NPAIR = (NT + 1) / 2;
    constexpr int R     = N / 64;
    constexpr int RS2   = N + N / 16 + 1;   // ODD float2 row stride
    constexpr int KLOOP = P / 4;            // pairs per wave (KLOOP*R == 8)
    const float NORM4   = 0.25f * 8.0f / (3.0f * (float)N);  // 1/(4*sum(w^2))

    const int tid   = threadIdx.x;
    const int lane  = tid & 63;
    const int wave  = tid >> 6;
    const int pair0 = tile * P;
    const int t0    = pair0 * 2;

    // packed table loads: 5 float4 per lane
    float sgn[6];
    vf2   twe[6];
    vf2   tw6 = {1,0}, tw7 = {1,0}, tw8 = {1,0};
    {
        const vf4* twp = (const vf4*)g_tab.lane_tw[lane];
        vf4 A = twp[0], B = twp[1], C = twp[2], D = twp[3], E = twp[4];
        twe[0] = {A.x, A.y}; twe[1] = {A.z, A.w};
        twe[2] = {B.x, B.y}; twe[3] = {B.z, B.w};
        twe[4] = {C.x, C.y}; twe[5] = {C.z, C.w};
        if constexpr (LOGN >= 7) tw6 = {D.x, D.y};
        if constexpr (LOGN >= 8) tw7 = {D.z, D.w};
        if constexpr (LOGN >= 9) tw8 = {E.x, E.y};
#pragma unroll
        for (int b = 0; b < 6; ++b) sgn[b] = ((lane >> b) & 1) ? -1.0f : 1.0f;
    }

    float wr[R];
#pragma unroll
    for (int r = 0; r < R; ++r) wr[r] = g_tab.win[LOGN - 6][r * 64 + lane];

    const float* xb = x + (size_t)bc * T_SAMPLES;

    vf2  d[KLOOP][R];
    bool act[KLOOP];

    // ---- load all pairs up front; contiguous per wave (L1 locality) ----
#pragma unroll
    for (int q = 0; q < KLOOP; ++q) {
        const int p  = wave * KLOOP + q;
        const int pg = pair0 + p;
        act[q] = (pg < NPAIR);
        if (act[q]) {
            const int t1 = 2 * pg, t2 = t1 + 1;
            const bool refl = (t1 == 0) || (t1 * HOP + N - 1 >= T_SAMPLES) || (t2 >= NT);
            if (!refl) {
                const float* src = xb + t1 * HOP - HOP;
#pragma unroll
                for (int r = 0; r < R; ++r) {
                    int n = r * 64 + lane;
                    vf2 v = { src[n], src[n + HOP] };
                    d[q][r] = v * wr[r];
                }
            } else {
#pragma unroll
                for (int r = 0; r < R; ++r) {
                    int n = r * 64 + lane;
                    int g = t1 * HOP + n - HOP;
                    g = (g < 0) ? -g : g;
                    g = (g >= T_SAMPLES) ? (2 * T_SAMPLES - 2 - g) : g;
                    float re = xb[g] * wr[r];
                    float im = 0.0f;
                    if (t2 < NT) {
                        int h = t2 * HOP + n - HOP;
                        h = (h < 0) ? -h : h;
                        h = (h >= T_SAMPLES) ? (2 * T_SAMPLES - 2 - h) : h;
                        im = xb[h] * wr[r];
                    }
                    d[q][r] = { re, im };
                }
            }
        } else {
#pragma unroll
            for (int r = 0; r < R; ++r) d[q][r] = vf2{0.0f, 0.0f};
        }
    }

    // ---- in-register DIF stages (bits 8,7,6), all pairs ----
    if constexpr (LOGN >= 9) {
        const vf2 u8 = { 0.70710678118654752f, -0.70710678118654752f };
#pragma unroll
        for (int q = 0; q < KLOOP; ++q) {
            vf2 tt = tw8;
#pragma unroll
            for (int r = 0; r < 4; ++r) {
                vf2 a = d[q][r], b = d[q][r + 4];
                d[q][r]     = a + b;
                d[q][r + 4] = cmul(a - b, tt);
                tt = cmul(tt, u8);
            }
        }
    }
    if constexpr (LOGN >= 8) {
        const vf2 t0_ = tw7;
        const vf2 t1_ = { tw7.y, -tw7.x };
#pragma unroll
        for (int q = 0; q < KLOOP; ++q) {
#pragma unroll
            for (int g = 0; g < R; g += 4) {
                { vf2 a = d[q][g],   b = d[q][g+2]; d[q][g]   = a + b; d[q][g+2] = cmul(a - b, t0_); }
                { vf2 a = d[q][g+1], b = d[q][g+3]; d[q][g+1] = a + b; d[q][g+3] = cmul(a - b, t1_); }
            }
        }
    }
    if constexpr (LOGN >= 7) {
#pragma unroll
        for (int q = 0; q < KLOOP; ++q) {
#pragma unroll
            for (int g = 0; g < R; g += 2) {
                vf2 a = d[q][g], b = d[q][g+1];
                d[q][g]   = a + b;
                d[q][g+1] = cmul(a - b, tw6);
            }
        }
    }

    // ---- cross-lane stages b=5..2 (shfl_xor), 8 independent chains ----
#pragma unroll
    for (int b = 5; b >= 2; --b) {
        const int   mask = 1 << b;
        const vf2   w    = twe[b];
        const float s    = sgn[b];
#pragma unroll
        for (int q = 0; q < KLOOP; ++q) {
#pragma unroll
            for (int r = 0; r < R; ++r) {
                vf2 p2;
                p2.x = __shfl_xor(d[q][r].x, mask, 64);
                p2.y = __shfl_xor(d[q][r].y, mask, 64);
                vf2 t  = p2 + d[q][r] * s;
                vf2 tr = { -t.y, t.x };
                d[q][r] = w.x * t + w.y * tr;
            }
        }
    }
    // ---- b=1: DPP quad_perm xor2 ----
    {
        const vf2   w = twe[1];
        const float s = sgn[1];
#pragma unroll
        for (int q = 0; q < KLOOP; ++q) {
#pragma unroll
            for (int r = 0; r < R; ++r) {
                vf2 p2 = { dppf<0x4E>(d[q][r].x), dppf<0x4E>(d[q][r].y) };
                vf2 t  = p2 + d[q][r] * s;
                vf2 tr = { -t.y, t.x };
                d[q][r] = w.x * t + w.y * tr;
            }
        }
    }
    // ---- b=0: DPP quad_perm xor1, twiddle == 1 ----
    {
        const float s = sgn[0];
#pragma unroll
        for (int q = 0; q < KLOOP; ++q) {
#pragma unroll
            for (int r = 0; r < R; ++r) {
                vf2 p2 = { dppf<0xB1>(d[q][r].x), dppf<0xB1>(d[q][r].y) };
                d[q][r] = p2 + d[q][r] * s;
            }
        }
    }

    // ---- scatter full Z (b64), bit-reversal resolved; (f>>4) swizzle ----
#pragma unroll
    for (int q = 0; q < KLOOP; ++q) {
        if (act[q]) {
            const int p = wave * KLOOP + q;
#pragma unroll
            for (int r = 0; r < R; ++r) {
                int idx = r * 64 + lane;
                int f   = (int)(__brev((unsigned)idx) >> (32 - LOGN));
                zb[p * RS2 + f + (f >> 4)] = d[q][r];
            }
        }
    }
    __syncthreads();

    // Hermitian separation: X1 (t even) + X2 (t odd) from one (Z[f],Z[N-f])
    // b64 read pair, packed into a single aligned half2 store.
    _Float16* sbase = spec + (size_t)bc * F * NTP;
    for (int e = tid; e < F * P; e += 256) {
        int f = e / P;                     // P is a power of two
        int p = e & (P - 1);
        int t = t0 + 2 * p;
        if (t < NT) {                      // matches act: pair0+p < NPAIR
            int fn = (N - f) & (N - 1);
            vf2 A = zb[p * RS2 + f  + (f  >> 4)];
            vf2 B = zb[p * RS2 + fn + (fn >> 4)];
            float rx = A.x + B.x, ry = A.y - B.y;      // X1 = (Z + conj(Zn))/2
            float sx = A.x - B.x, sy = A.y + B.y;      // X2 = (Z - conj(Zn))/2i
            vh2 pv = { (_Float16)((rx * rx + ry * ry) * NORM4),
                       (_Float16)((sx * sx + sy * sy) * NORM4) };   // last col X2 lands in pad
            *(vh2*)(sbase + (size_t)f * NTP + t) = pv;
        }
    }
}

// Fused kernel, uniform 9 tiles per resolution:
// bx in [0,9) N=64 | [9,18) N=128 | [18,27) N=256 | [27,36) N=512
__global__ __launch_bounds__(256) void fft_all_kernel(const float* __restrict__ x,
                                                      _Float16* __restrict__ ws) {
    __shared__ vf2 smem[2208];   // max P*RS2: res0 32*69 = 2208 float2 = 17664 B
    const int bx = blockIdx.x;
    const int bc = blockIdx.y;
    if (bx < 9)        fft_tile_body<6, 32>(x, ws + OFF0, bx,      bc, smem);
    else if (bx < 18)  fft_tile_body<7, 16>(x, ws + OFF1, bx - 9,  bc, smem);
    else if (bx < 27)  fft_tile_body<8, 8> (x, ws + OFF2, bx - 18, bc, smem);
    else               fft_tile_body<9, 4> (x, ws + OFF3, bx - 27, bc, smem);
}

// 2 output rows (i) x 4 columns (j) per thread: the 3 ti magic-muls are shared
// across rows, the fi muls across columns. res-0 gather = aligned half4/row.
__global__ __launch_bounds__(256) void remap_max_kernel(const _Float16* __restrict__ ws,
                                                        float* __restrict__ out) {
    const int JG    = 129;                    // ceil(513/4)
    const int IG    = 129;                    // ceil(257/2)
    const int total = BC * IG * JG;
    int idx = blockIdx.x * 256 + threadIdx.x;
    if (idx >= total) return;
    int jg  = idx % JG;
    int rem = idx / JG;
    int ig  = rem % IG;
    int bc  = rem / IG;
    int j0  = jg * 4;
    int i0  = ig * 2;
    const bool fullj = (j0 + 3 < NUM_TIMES);
    const int  ni    = (i0 + 1 < NUM_FREQS) ? 2 : 1;

    float mv[2][4];
#pragma unroll
    for (int ii = 0; ii < 2; ++ii) {
        if (ii < ni) {   // r0: ti == j; stride 516, j0 %4==0 -> aligned half4
            int fi = ((i0 + ii) * 33) / NUM_FREQS;
            const _Float16* p = ws + OFF0 + ((size_t)bc * 33 + fi) * 516 + j0;
            if (fullj) {
                vh4 v = *(const vh4*)p;
                mv[ii][0] = (float)v.x; mv[ii][1] = (float)v.y;
                mv[ii][2] = (float)v.z; mv[ii][3] = (float)v.w;
            } else {
                mv[ii][0] = (float)p[0];
                mv[ii][1] = mv[ii][2] = mv[ii][3] = 0.0f;
            }
        }
    }

    const int fi1a = (i0 * 65) / NUM_FREQS,  fi1b = ((i0 + 1) * 65) / NUM_FREQS;
    const int fi2a = (i0 * 129) / NUM_FREQS, fi2b = ((i0 + 1) * 129) / NUM_FREQS;
    const int fi3a = i0, fi3b = i0 + 1;      // 257 freqs -> identity

#pragma unroll
    for (int k = 0; k < 4; ++k) {
        int j = j0 + k;
        if (j < NUM_TIMES) {
            int ti1 = (j * 257) / NUM_TIMES;
            int ti2 = (j * 129) / NUM_TIMES;
            int ti3 = (j * 65)  / NUM_TIMES;
            const _Float16* b1 = ws + OFF1 + (size_t)bc * 65  * 260 + ti1;
            const _Float16* b2 = ws + OFF2 + (size_t)bc * 129 * 132 + ti2;
            const _Float16* b3 = ws + OFF3 + (size_t)bc * 257 * 68  + ti3;
            mv[0][k] = fmaxf(mv[0][k], (float)b1[(size_t)fi1a * 260]);
            mv[0][k] = fmaxf(mv[0][k], (float)b2[(size_t)fi2a * 132]);
            mv[0][k] = fmaxf(mv[0][k], (float)b3[(size_t)fi3a * 68]);
            if (ni == 2) {
                mv[1][k] = fmaxf(mv[1][k], (float)b1[(size_t)fi1b * 260]);
                mv[1][k] = fmaxf(mv[1][k], (float)b2[(size_t)fi2b * 132]);
                mv[1][k] = fmaxf(mv[1][k], (float)b3[(size_t)fi3b * 68]);
            }
        }
    }

#pragma unroll
    for (int ii = 0; ii < 2; ++ii) {
        if (ii < ni) {
            float* po = out + ((size_t)bc * NUM_FREQS + i0 + ii) * NUM_TIMES + j0;
            if (fullj) {
                vf4 v = { mv[ii][0], mv[ii][1], mv[ii][2], mv[ii][3] };
                *(vf4u*)po = v;
            } else {
                po[0] = mv[ii][0];
            }
        }
    }
}

extern "C" void kernel_launch(void* const* d_in, const int* in_sizes, int n_in,
                              void* d_out, int out_size, void* d_ws, size_t ws_size,
                              hipStream_t stream) {
    const float* x = (const float*)d_in[0];
    _Float16* ws = (_Float16*)d_ws;
    float* out = (float*)d_out;

    fft_all_kernel<<<dim3(36, BC), 256, 0, stream>>>(x, ws);

    const int total = BC * 129 * 129;
    remap_max_kernel<<<(total + 255) / 256, 256, 0, stream>>>(ws, out);
}